// Round 7
// baseline (809.838 us; speedup 1.0000x reference)
//
#include <hip/hip_runtime.h>

#define NU 100000
#define NS 50000
#define NG 50
#define NW 20000
#define NT 10
#define CDIM 64
#define FDIM 384

typedef short bf16x8 __attribute__((ext_vector_type(8)));
typedef float f32x4 __attribute__((ext_vector_type(4)));
typedef unsigned short ushort;
typedef unsigned int uint;

#define CHUNK 128
#define CSHIFT 7
#define CMASK 127
#define NBINS 2503      // 391+782+391+391+157+391
#define PSTRIDE 800
#define BTOT 1216       // fill/hist blocks (512+512+64+32+32+64)
#define CTOT 2503
#define W_TOTAL 188416
#define WPB 736         // wprep blocks
#define G_GEN 512       // small1 genre blocks
#define G_TYP 256       // small1 type blocks
#define SCANB_BLK 626   // ceil(NBINS/4) wave-parallel scan blocks

struct PrepArgs {
  const int* src[6];
  const int* dst[6];
  int E[6];
  int nchunk[6];
  int nb[6];
  int cbase[7];
  int bbase[7];
  int cstart[7];
  int* partial;   // [BTOT][PSTRIDE]
  int* chunktot;  // [NBINS]
  int* choff;     // [NBINS + 6]
  int* bucket[6];
  int* adj[6];
  int* off[6];
};

struct WArgs {
  const float* Wu; const float* Wsp;
  const float* Wl1; const float* Wr1;
  const float* Wl2; const float* Wr2;
  ushort* S;
};

// ---------------- prep bodies ----------------
__device__ __forceinline__ void hist_body(const PrepArgs& a, int b, int t, int* bins) {
  int ty = 0;
  while (b >= a.bbase[ty + 1]) ++ty;
  int bl = b - a.bbase[ty], B = a.bbase[ty + 1] - a.bbase[ty];
  int n = a.nchunk[ty], E = a.E[ty];
  const int* __restrict__ dst = a.dst[ty];
  for (int i = t; i < n; i += 256) bins[i] = 0;
  __syncthreads();
  for (int i = bl * 256 + t; i < E; i += B * 256) atomicAdd(&bins[dst[i] >> CSHIFT], 1);
  __syncthreads();
  int* row = a.partial + (size_t)b * PSTRIDE;
  for (int i = t; i < n; i += 256) row[i] = bins[i];
}

// Wave-parallel scan over fill blocks for one bin: lane covers up to 8
// consecutive blocks (independent loads), register prefix, 6-step shfl scan.
__device__ __forceinline__ void scanb_wave_body(const PrepArgs& a, int bin, int lane) {
  if (bin >= NBINS) return;
  int ty = 0;
  while (bin >= a.cbase[ty + 1]) ++ty;
  int l = bin - a.cbase[ty];
  int b0 = a.bbase[ty], B = a.bbase[ty + 1] - b0;
  int per = (B + 63) >> 6;   // 1..8
  int* pbase = a.partial + l;
  int v[8];
  int sum = 0;
#pragma unroll
  for (int k = 0; k < 8; ++k) {
    int idx = lane * per + k;
    int val = (k < per && idx < B) ? pbase[(size_t)(b0 + idx) * PSTRIDE] : 0;
    v[k] = sum; sum += val;
  }
  int run = sum;
#pragma unroll
  for (int d = 1; d < 64; d <<= 1) {
    int u = __shfl_up(run, d, 64);
    if (lane >= d) run += u;
  }
  int excl = run - sum;
#pragma unroll
  for (int k = 0; k < 8; ++k) {
    int idx = lane * per + k;
    if (k < per && idx < B) pbase[(size_t)(b0 + idx) * PSTRIDE] = excl + v[k];
  }
  if (lane == 63) a.chunktot[bin] = run;
}

__device__ __forceinline__ void scanc_body(const PrepArgs& a, int ty, int t, int* sc) {
  int n = a.nchunk[ty];
  int chunk = (n + 255) / 256;
  int lo = t * chunk, hi = min(n, lo + chunk);
  const int* __restrict__ cnt = a.chunktot + a.cbase[ty];
  int s = 0;
  for (int i = lo; i < hi; ++i) s += cnt[i];
  sc[t] = s;
  __syncthreads();
  for (int d = 1; d < 256; d <<= 1) {
    int u = (t >= d) ? sc[t - d] : 0;
    __syncthreads();
    sc[t] += u;
    __syncthreads();
  }
  int* choff = a.choff + a.cbase[ty] + ty;
  int carry = (t > 0) ? sc[t - 1] : 0;
  for (int i = lo; i < hi; ++i) { choff[i] = carry; carry += cnt[i]; }
  if (t == 255) choff[n] = sc[255];
}

__device__ __forceinline__ void fill_body(const PrepArgs& a, int b, int t, int* bins, int* base) {
  int ty = 0;
  while (b >= a.bbase[ty + 1]) ++ty;
  int bl = b - a.bbase[ty], B = a.bbase[ty + 1] - a.bbase[ty];
  int n = a.nchunk[ty], E = a.E[ty];
  const int* __restrict__ dst = a.dst[ty];
  const int* __restrict__ src = a.src[ty];
  int* __restrict__ bucket = a.bucket[ty];
  const int* choff = a.choff + a.cbase[ty] + ty;
  const int* prow = a.partial + (size_t)b * PSTRIDE;
  for (int i = t; i < n; i += 256) { bins[i] = 0; base[i] = choff[i] + prow[i]; }
  __syncthreads();
  for (int i = bl * 256 + t; i < E; i += B * 256) {
    int d = dst[i];
    int s = src[i];
    int l = d >> CSHIFT;
    int r = atomicAdd(&bins[l], 1);
    bucket[base[l] + r] = (s << CSHIFT) | (d & CMASK);
  }
}

__device__ __forceinline__ void csr_body(const PrepArgs& a, int b, int t,
                                         int* bins, int* sc, int* basea) {
  int ty = 0;
  while (b >= a.cstart[ty + 1]) ++ty;
  int c = b - a.cstart[ty];
  const int* __restrict__ bucket = a.bucket[ty];
  const int* choff = a.choff + a.cbase[ty] + ty;
  int beg = choff[c], end = choff[c + 1];
  if (t < CHUNK) bins[t] = 0;
  __syncthreads();
  for (int i = beg + t; i < end; i += 256) atomicAdd(&bins[bucket[i] & CMASK], 1);
  __syncthreads();
  int v = (t < CHUNK) ? bins[t] : 0;
  if (t < CHUNK) sc[t] = v;
  __syncthreads();
#pragma unroll
  for (int d = 1; d < CHUNK; d <<= 1) {
    int u = (t < CHUNK && t >= d) ? sc[t - d] : 0;
    __syncthreads();
    if (t < CHUNK) sc[t] += u;
    __syncthreads();
  }
  if (t < CHUNK) { basea[t] = beg + sc[t] - v; bins[t] = basea[t]; }
  __syncthreads();
  int gbase = c * CHUNK;
  int nb = a.nb[ty];
  if (t < CHUNK && gbase + t < nb) a.off[ty][gbase + t] = basea[t];
  if (b == a.cstart[ty + 1] - 1 && t == 0) a.off[ty][nb] = choff[a.nchunk[ty]];
  int* __restrict__ adj = a.adj[ty];
  for (int i = beg + t; i < end; i += 256) {
    int pk = bucket[i];
    int r = atomicAdd(&bins[pk & CMASK], 1);
    adj[r] = pk >> CSHIFT;
  }
}

// ---------------- weight split (pre-swizzled to MFMA B-fragment order) ------
__device__ __forceinline__ int swz_src(int u, int F) {
  int p = u >> 11;
  int nt = (u >> 9) & 3;
  int lane = (u >> 3) & 63;
  int j = u & 7;
  int row = nt * 16 + (lane & 15);
  int col = p * 32 + ((lane >> 4) << 3) + j;
  return row * F + col;
}

__device__ __forceinline__ void wprep_body(const WArgs& w, int i) {
  if (i >= W_TOTAL) return;
  float v;
  size_t hbase, lbase;
  int u;
  if (i < 24576) {
    u = i; hbase = 0; lbase = 24576;
    v = w.Wu[swz_src(u, FDIM)];
  } else if (i < 49152) {
    u = i - 24576; hbase = 49152; lbase = 73728;
    v = w.Wsp[swz_src(u, FDIM)];
  } else {
    int j = i - 49152;
    int layer = j / 69632;
    j %= 69632;
    const float* Wl = layer ? w.Wl2 : w.Wl1;
    const float* Wr = layer ? w.Wr2 : w.Wr1;
    size_t base = 98304 + (size_t)layer * 139264;
    if (j < 32768) {
      int s = j >> 12; u = j & 4095;
      hbase = base + (size_t)s * 4096; lbase = base + 32768 + (size_t)s * 4096;
      v = Wl[s * 4096 + swz_src(u, 64)];
    } else if (j < 65536) {
      int q = j - 32768; int s = q >> 12; u = q & 4095;
      hbase = base + 65536 + (size_t)s * 4096; lbase = base + 98304 + (size_t)s * 4096;
      v = Wr[s * 4096 + swz_src(u, 64)];
    } else {
      u = j - 65536;
      hbase = base + 131072; lbase = base + 135168;
      int si = swz_src(u, 64);
      v = Wr[si] + Wr[8192 + si] + Wr[16384 + si] + Wr[24576 + si];
    }
  }
  uint b = __float_as_uint(v);
  uint h = b & 0xFFFF0000u;
  float r = v - __uint_as_float(h);
  w.S[hbase + u] = (ushort)(h >> 16);
  w.S[lbase + u] = (ushort)(__float_as_uint(r) >> 16);
}

// ---------------- CSR gather (16-lane-group, float4 lanes) ----------------
__device__ __forceinline__ void csr_gather_body(const int* __restrict__ adj,
                                                const int* __restrict__ off,
                                                const float* __restrict__ x,
                                                float* __restrict__ out,
                                                int row, int l4, int gbase) {
  int beg = off[row], deg = off[row + 1] - beg;
  float4 a0 = {0.f, 0.f, 0.f, 0.f}, a1 = a0, a2 = a0, a3 = a0;
  int j = 0;
  while (j < deg) {
    int rem = min(deg - j, 16);
    int av = (l4 < rem) ? adj[beg + j + l4] : 0;
    int k = 0;
    for (; k + 4 <= rem; k += 4) {
      int s0 = __shfl(av, gbase + k + 0, 64);
      int s1 = __shfl(av, gbase + k + 1, 64);
      int s2 = __shfl(av, gbase + k + 2, 64);
      int s3 = __shfl(av, gbase + k + 3, 64);
      float4 v0 = *(const float4*)(x + (((size_t)s0) << 6) + l4 * 4);
      float4 v1 = *(const float4*)(x + (((size_t)s1) << 6) + l4 * 4);
      float4 v2 = *(const float4*)(x + (((size_t)s2) << 6) + l4 * 4);
      float4 v3 = *(const float4*)(x + (((size_t)s3) << 6) + l4 * 4);
      a0.x += v0.x; a0.y += v0.y; a0.z += v0.z; a0.w += v0.w;
      a1.x += v1.x; a1.y += v1.y; a1.z += v1.z; a1.w += v1.w;
      a2.x += v2.x; a2.y += v2.y; a2.z += v2.z; a2.w += v2.w;
      a3.x += v3.x; a3.y += v3.y; a3.z += v3.z; a3.w += v3.w;
    }
    for (; k < rem; ++k) {
      int s0 = __shfl(av, gbase + k, 64);
      float4 v0 = *(const float4*)(x + (((size_t)s0) << 6) + l4 * 4);
      a0.x += v0.x; a0.y += v0.y; a0.z += v0.z; a0.w += v0.w;
    }
    j += rem;
  }
  float4 s;
  s.x = (a0.x + a1.x) + (a2.x + a3.x);
  s.y = (a0.y + a1.y) + (a2.y + a3.y);
  s.z = (a0.z + a1.z) + (a2.z + a3.z);
  s.w = (a0.w + a1.w) + (a2.w + a3.w);
  float4 o = {0.f, 0.f, 0.f, 0.f};
  if (deg > 0) {
    float d = (float)deg;
    o.x = s.x / d; o.y = s.y / d; o.z = s.z / d; o.w = s.w / d;
  }
  *(float4*)(out + (((size_t)row) << 6) + l4 * 4) = o;
}

struct AggArgs {
  const int* adj[6];
  const int* off[6];
  const float* x[6];
  float* out[6];
  int N[6];
  int start[7];
  int ntask;
};

__global__ __launch_bounds__(256) void agg_fused(AggArgs a) {
  int b = blockIdx.x;
  int ti = 0;
  while (b >= a.start[ti + 1]) ++ti;
  int row = (b - a.start[ti]) * 16 + (threadIdx.x >> 4);
  int l4 = threadIdx.x & 15;
  int gbase = (threadIdx.x & 63) & 48;   // group base lane within wave
  if (row >= a.N[ti]) return;
  csr_gather_body(a.adj[ti], a.off[ti], a.x[ti], a.out[ti], row, l4, gbase);
}

// ---------------- small-dst agg (two-stage) ----------------
struct SmallT { const int* src; const int* dst; int E; const float* x;
                float* partial; int* pcnt; int nd; int G; };
struct Small2T { const float* partial; const int* pcnt; float* out; int nd; int G; };

__device__ __forceinline__ void small1_body(const SmallT& s, int blk, int t, int* smem) {
  float* acc = (float*)smem;
  int* cnt = smem + s.nd * CDIM;
  int lane = t & 63, wv = t >> 6;
  for (int i = t; i < s.nd * CDIM; i += 256) acc[i] = 0.f;
  for (int i = t; i < s.nd; i += 256) cnt[i] = 0;
  __syncthreads();
  const int* __restrict__ src = s.src;
  const int* __restrict__ dst = s.dst;
  const float* __restrict__ x = s.x;
  int E = s.E;
  for (int j0 = (blk * 4 + wv) * 64; j0 < E; j0 += s.G * 256) {
    int myj = j0 + lane;
    int sv = 0, dv = 0;
    if (myj < E) { sv = src[myj]; dv = dst[myj]; }
    int m = min(64, E - j0);
    int j = 0;
    for (; j + 4 <= m; j += 4) {
      int s0 = __shfl(sv, j, 64), s1 = __shfl(sv, j + 1, 64);
      int s2 = __shfl(sv, j + 2, 64), s3 = __shfl(sv, j + 3, 64);
      int d0 = __shfl(dv, j, 64), d1 = __shfl(dv, j + 1, 64);
      int d2 = __shfl(dv, j + 2, 64), d3 = __shfl(dv, j + 3, 64);
      float v0 = x[(size_t)s0 * CDIM + lane];
      float v1 = x[(size_t)s1 * CDIM + lane];
      float v2 = x[(size_t)s2 * CDIM + lane];
      float v3 = x[(size_t)s3 * CDIM + lane];
      atomicAdd(&acc[d0 * CDIM + lane], v0);
      atomicAdd(&acc[d1 * CDIM + lane], v1);
      atomicAdd(&acc[d2 * CDIM + lane], v2);
      atomicAdd(&acc[d3 * CDIM + lane], v3);
      if (lane == 0) {
        atomicAdd(&cnt[d0], 1); atomicAdd(&cnt[d1], 1);
        atomicAdd(&cnt[d2], 1); atomicAdd(&cnt[d3], 1);
      }
    }
    for (; j < m; ++j) {
      int sj = __shfl(sv, j, 64), dj = __shfl(dv, j, 64);
      atomicAdd(&acc[dj * CDIM + lane], x[(size_t)sj * CDIM + lane]);
      if (lane == 0) atomicAdd(&cnt[dj], 1);
    }
  }
  __syncthreads();
  float* po = s.partial + (size_t)blk * s.nd * CDIM;
  for (int i = t; i < s.nd * CDIM; i += 256) po[i] = acc[i];
  int* pc = s.pcnt + blk * s.nd;
  for (int i = t; i < s.nd; i += 256) pc[i] = cnt[i];
}

__device__ __forceinline__ void small2_body(const Small2T& s, int d, int t, int* smem) {
  float* red = (float*)smem;          // [4][64]
  int* redc = smem + 256;             // [4]
  int c = t & 63, sl = t >> 6;
  float sum = 0.f;
  int k = 0;
  for (int g = sl; g < s.G; g += 4) {
    sum += s.partial[(size_t)g * s.nd * CDIM + d * CDIM + c];
    if (c == 0) k += s.pcnt[g * s.nd + d];
  }
  red[sl * 64 + c] = sum;
  if (c == 0) redc[sl] = k;
  __syncthreads();
  if (sl == 0) {
    float tot = red[c] + red[64 + c] + red[128 + c] + red[192 + c];
    int kt = redc[0] + redc[1] + redc[2] + redc[3];
    s.out[d * CDIM + c] = (kt > 0) ? tot / (float)kt : 0.f;
  }
}

// ---------------- MFMA GEMM (bf16 hi/lo, pre-swizzled W) ----------------
struct GSeg { const float* A; const ushort* Wh; const ushort* Wl; int F; };
struct GArgs {
  GSeg seg[5];
  const float* bias[4];
  float* out;
  int nseg, nbias, M, relu;
};
struct GemmMulti { GArgs g[5]; int start[6]; int n; };

__device__ __forceinline__ void split8(const float* __restrict__ p, bf16x8& hi, bf16x8& lo) {
  float4 v0 = *(const float4*)p;
  float4 v1 = *(const float4*)(p + 4);
  float a[8] = {v0.x, v0.y, v0.z, v0.w, v1.x, v1.y, v1.z, v1.w};
  union { uint u[4]; bf16x8 v; } H, L;
#pragma unroll
  for (int i = 0; i < 4; ++i) {
    uint u0 = __float_as_uint(a[2 * i]), u1 = __float_as_uint(a[2 * i + 1]);
    uint h0 = u0 & 0xFFFF0000u, h1 = u1 & 0xFFFF0000u;
    float r0 = a[2 * i] - __uint_as_float(h0);
    float r1 = a[2 * i + 1] - __uint_as_float(h1);
    H.u[i] = (h0 >> 16) | h1;
    L.u[i] = ((__float_as_uint(r0) & 0xFFFF0000u) >> 16) | (__float_as_uint(r1) & 0xFFFF0000u);
  }
  hi = H.v;
  lo = L.v;
}

__device__ __forceinline__ void mfma_body(const GArgs& g, int mb, int tid) {
  const int lane = tid & 63, wv = tid >> 6;
  const int ln = lane & 15, quad = lane >> 4;
  const int m0 = mb * 64;
  f32x4 acc[4];
#pragma unroll
  for (int nt = 0; nt < 4; ++nt) acc[nt] = (f32x4){0.f, 0.f, 0.f, 0.f};

  const int ar = min(m0 + 16 * wv + ln, g.M - 1);

  for (int s = 0; s < g.nseg; ++s) {
    const float* __restrict__ A = g.seg[s].A;
    const ushort* __restrict__ whl = g.seg[s].Wh + (size_t)lane * 8;
    const ushort* __restrict__ wll = g.seg[s].Wl + (size_t)lane * 8;
    const int F = g.seg[s].F;
    const float* ap = A + (size_t)ar * F + quad * 8;
    for (int k0 = 0; k0 < F; k0 += 32) {
      bf16x8 ah, al;
      split8(ap + k0, ah, al);
      const size_t pb = (size_t)(k0 >> 5) * 2048;
#pragma unroll
      for (int nt = 0; nt < 4; ++nt) {
        bf16x8 bh = *(const bf16x8*)(whl + pb + nt * 512);
        bf16x8 bl = *(const bf16x8*)(wll + pb + nt * 512);
        acc[nt] = __builtin_amdgcn_mfma_f32_16x16x32_bf16(ah, bh, acc[nt], 0, 0, 0);
        acc[nt] = __builtin_amdgcn_mfma_f32_16x16x32_bf16(al, bh, acc[nt], 0, 0, 0);
        acc[nt] = __builtin_amdgcn_mfma_f32_16x16x32_bf16(ah, bl, acc[nt], 0, 0, 0);
      }
    }
  }

#pragma unroll
  for (int nt = 0; nt < 4; ++nt) {
    int c = nt * 16 + ln;
    float b = 0.f;
    for (int i = 0; i < g.nbias; ++i) b += g.bias[i][c];
#pragma unroll
    for (int r = 0; r < 4; ++r) {
      int m = m0 + 16 * wv + quad * 4 + r;
      if (m < g.M) {
        float o = acc[nt][r] + b;
        if (g.relu) o = fmaxf(o, 0.f);
        g.out[(size_t)m * CDIM + c] = o;
      }
    }
  }
}

__global__ __launch_bounds__(256) void gemm_multi_k(GemmMulti gm) {
  int b = blockIdx.x;
  int i = 0;
  while (b >= gm.start[i + 1]) ++i;
  mfma_body(gm.g[i], b - gm.start[i], threadIdx.x);
}

// ---------------- fused stage kernels ----------------
__global__ __launch_bounds__(256) void s1_k(PrepArgs pa, WArgs wa) {
  __shared__ int smem[PSTRIDE];
  int b = blockIdx.x;
  if (b < BTOT) hist_body(pa, b, threadIdx.x, smem);
  else wprep_body(wa, (b - BTOT) * 256 + threadIdx.x);
}

__global__ __launch_bounds__(256) void s2_k(PrepArgs pa, GArgs g) {
  int b = blockIdx.x;
  if (b < SCANB_BLK) scanb_wave_body(pa, b * 4 + (threadIdx.x >> 6), threadIdx.x & 63);
  else mfma_body(g, b - SCANB_BLK, threadIdx.x);
}

__global__ __launch_bounds__(256) void s3_k(PrepArgs pa, GArgs g) {
  __shared__ int smem[256];
  int b = blockIdx.x;
  if (b < 6) scanc_body(pa, b, threadIdx.x, smem);
  else mfma_body(g, b - 6, threadIdx.x);
}

__global__ __launch_bounds__(256) void s4_k(PrepArgs pa, SmallT sg, SmallT st) {
  __shared__ int smem[3264];
  int b = blockIdx.x;
  if (b < BTOT) fill_body(pa, b, threadIdx.x, smem, smem + PSTRIDE);
  else if (b < BTOT + G_GEN) small1_body(sg, b - BTOT, threadIdx.x, smem);
  else small1_body(st, b - BTOT - G_GEN, threadIdx.x, smem);
}

__global__ __launch_bounds__(256) void s5_k(PrepArgs pa, Small2T g2, Small2T t2) {
  __shared__ int smem[384];
  int b = blockIdx.x;
  if (b < CTOT) csr_body(pa, b, threadIdx.x, smem, smem + CHUNK, smem + 2 * CHUNK);
  else if (b < CTOT + NG) small2_body(g2, b - CTOT, threadIdx.x, smem);
  else small2_body(t2, b - CTOT - NG, threadIdx.x, smem);
}

// ---------------- scoring ----------------
__global__ __launch_bounds__(256) void score_k(const int* __restrict__ eli, int E,
                                               const float* __restrict__ xu,
                                               const float* __restrict__ xs,
                                               float* __restrict__ out) {
  long long gid = (long long)blockIdx.x * 256 + threadIdx.x;
  int e = (int)(gid >> 6);
  int c = (int)(gid & 63);
  if (e < E) {
    int u = eli[e];
    int sv = eli[E + e];
    float p = xu[(size_t)u * CDIM + c] * xs[(size_t)sv * CDIM + c];
#pragma unroll
    for (int off = 32; off > 0; off >>= 1) p += __shfl_down(p, off, 64);
    if (c == 0) out[e] = p;
  }
}

extern "C" void kernel_launch(void* const* d_in, const int* in_sizes, int n_in,
                              void* d_out, int out_size, void* d_ws, size_t ws_size,
                              hipStream_t stream) {
  const float* reviews  = (const float*)d_in[0];
  const float* overview = (const float*)d_in[1];
  const float* g_emb    = (const float*)d_in[2];
  const float* w_emb    = (const float*)d_in[3];
  const float* t_emb    = (const float*)d_in[4];
  const float* Wu  = (const float*)d_in[5];
  const float* bu  = (const float*)d_in[6];
  const float* Wsp = (const float*)d_in[7];
  const float* bs  = (const float*)d_in[8];
  const float* Wl1 = (const float*)d_in[9];
  const float* bl1 = (const float*)d_in[10];
  const float* Wr1 = (const float*)d_in[11];
  const float* Wl2 = (const float*)d_in[12];
  const float* bl2 = (const float*)d_in[13];
  const float* Wr2 = (const float*)d_in[14];
  const int* e_u2s = (const int*)d_in[15];
  const int* e_g2s = (const int*)d_in[16];
  const int* e_w2s = (const int*)d_in[17];
  const int* e_t2s = (const int*)d_in[18];
  const int* eli   = (const int*)d_in[19];
  const int E_u = in_sizes[15] / 2;
  const int E_g = in_sizes[16] / 2;
  const int E_w = in_sizes[17] / 2;
  const int E_t = in_sizes[18] / 2;
  const int E_l = in_sizes[19] / 2;

  // ---- workspace (ws_size ~614MB; we use ~205MB) ----
  float* ws = (float*)d_ws;
  size_t off = 0;
  auto take = [&](size_t n) { float* p = ws + off; off += n; return p; };
  float* x0u = take((size_t)NU * CDIM);
  float* x0s = take((size_t)NS * CDIM);
  float* x1u = take((size_t)NU * CDIM);
  float* x1s = take((size_t)NS * CDIM);
  float* x1g = take((size_t)NG * CDIM);
  float* x1w = take((size_t)NW * CDIM);
  float* x1t = take((size_t)NT * CDIM);
  float* aggS0 = take((size_t)NS * CDIM);
  float* aggS2 = take((size_t)NS * CDIM);
  float* aggS4 = take((size_t)NS * CDIM);
  float* aggS6 = take((size_t)NS * CDIM);
  float* agg1  = take((size_t)NU * CDIM);   // standalone (concurrent with aggS*)
  float* agg5  = take((size_t)NW * CDIM);
  float* agg3  = take((size_t)NG * CDIM);
  float* agg7  = take((size_t)NT * CDIM);
  float* spartG = take((size_t)G_GEN * NG * CDIM);
  int* spcntG   = (int*)take((size_t)G_GEN * NG);
  float* spartT = take((size_t)G_TYP * NT * CDIM);
  int* spcntT   = (int*)take((size_t)G_TYP * NT);
  ushort* wsplit = (ushort*)take((size_t)W_TOTAL);  // 2*W_TOTAL ushorts
  int* bkt0 = (int*)take(E_u);
  int* bkt1 = (int*)take(E_u);
  int* bkt2 = (int*)take(E_g);
  int* bkt3 = (int*)take(E_w);
  int* bkt4 = (int*)take(E_w);
  int* bkt5 = (int*)take(E_t);
  int* adj0 = (int*)take(E_u);
  int* adj1 = (int*)take(E_u);
  int* adj2 = (int*)take(E_g);
  int* adj3 = (int*)take(E_w);
  int* adj4 = (int*)take(E_w);
  int* adj5 = (int*)take(E_t);
  int* off0 = (int*)take(NS + 1);
  int* off1 = (int*)take(NU + 1);
  int* off2 = (int*)take(NS + 1);
  int* off3 = (int*)take(NS + 1);
  int* off4 = (int*)take(NW + 1);
  int* off5 = (int*)take(NS + 1);
  int* partial  = (int*)take((size_t)BTOT * PSTRIDE);
  int* chunktot = (int*)take(NBINS);
  int* choffG   = (int*)take(NBINS + 6);
  float* x2u = x0u;
  float* x2s = x0s;

  // split-weight region offsets (ushort units)
  const ushort* WuH = wsplit + 0;
  const ushort* WuL = wsplit + 24576;
  const ushort* WsH = wsplit + 49152;
  const ushort* WsL = wsplit + 73728;
  auto WlH = [&](int layer, int seg) { return wsplit + 98304 + (size_t)layer * 139264 + (size_t)seg * 4096; };
  auto WlL = [&](int layer, int seg) { return wsplit + 98304 + (size_t)layer * 139264 + 32768 + (size_t)seg * 4096; };
  auto WrH = [&](int layer, int seg) { return wsplit + 98304 + (size_t)layer * 139264 + 65536 + (size_t)seg * 4096; };
  auto WrL = [&](int layer, int seg) { return wsplit + 98304 + (size_t)layer * 139264 + 98304 + (size_t)seg * 4096; };
  auto WrsH = [&](int layer) { return wsplit + 98304 + (size_t)layer * 139264 + 131072; };
  auto WrsL = [&](int layer) { return wsplit + 98304 + (size_t)layer * 139264 + 135168; };

  // ---- prep args ----
  PrepArgs pa{};
  const int* bsrc[6] = {e_u2s, e_u2s + E_u, e_g2s, e_w2s, e_w2s + E_w, e_t2s};
  const int* bdst[6] = {e_u2s + E_u, e_u2s, e_g2s + E_g, e_w2s + E_w, e_w2s, e_t2s + E_t};
  int bE[6]  = {E_u, E_u, E_g, E_w, E_w, E_t};
  int nch[6] = {391, 782, 391, 391, 157, 391};
  int cb[7]  = {0, 391, 1173, 1564, 1955, 2112, 2503};
  int bpt[6] = {512, 512, 64, 32, 32, 64};
  int nbT[6] = {NS, NU, NS, NS, NW, NS};
  int* bkts[6] = {bkt0, bkt1, bkt2, bkt3, bkt4, bkt5};
  int* adjs[6] = {adj0, adj1, adj2, adj3, adj4, adj5};
  int* offs[6] = {off0, off1, off2, off3, off4, off5};
  int bb = 0, cs = 0;
  for (int i = 0; i < 6; ++i) {
    pa.src[i] = bsrc[i]; pa.dst[i] = bdst[i]; pa.E[i] = bE[i];
    pa.nchunk[i] = nch[i]; pa.nb[i] = nbT[i]; pa.cbase[i] = cb[i];
    pa.bbase[i] = bb; bb += bpt[i];
    pa.cstart[i] = cs; cs += nch[i];
    pa.bucket[i] = bkts[i]; pa.adj[i] = adjs[i]; pa.off[i] = offs[i];
  }
  pa.cbase[6] = cb[6]; pa.bbase[6] = bb; pa.cstart[6] = cs;
  pa.partial = partial; pa.chunktot = chunktot; pa.choff = choffG;

  WArgs wa{Wu, Wsp, Wl1, Wr1, Wl2, Wr2, wsplit};

  // ---- S1: hist + weight split ----
  s1_k<<<BTOT + WPB, 256, 0, stream>>>(pa, wa);

  // ---- S2: scanb (wave-parallel) + NU projection ----
  {
    GArgs g{};
    g.seg[0] = {reviews, WuH, WuL, FDIM}; g.nseg = 1;
    g.bias[0] = bu; g.nbias = 1;
    g.out = x0u; g.M = NU; g.relu = 0;
    s2_k<<<SCANB_BLK + (NU + 63) / 64, 256, 0, stream>>>(pa, g);
  }
  // ---- S3: scanc + NS projection ----
  {
    GArgs g{};
    g.seg[0] = {overview, WsH, WsL, FDIM}; g.nseg = 1;
    g.bias[0] = bs; g.nbias = 1;
    g.out = x0s; g.M = NS; g.relu = 0;
    s3_k<<<6 + (NS + 63) / 64, 256, 0, stream>>>(pa, g);
  }
  // ---- S4: fill + small1(genres) + small1(type) ----
  {
    SmallT sg{e_g2s, e_g2s + E_g, E_g, x0s, spartG, spcntG, NG, G_GEN};
    SmallT st{e_t2s, e_t2s + E_t, E_t, x0s, spartT, spcntT, NT, G_TYP};
    sg.src = e_g2s + E_g; sg.dst = e_g2s;
    st.src = e_t2s + E_t; st.dst = e_t2s;
    s4_k<<<BTOT + G_GEN + G_TYP, 256, 0, stream>>>(pa, sg, st);
  }
  // ---- S5: csr + small2(genres) + small2(type) ----
  {
    Small2T g2{spartG, spcntG, agg3, NG, G_GEN};
    Small2T t2{spartT, spcntT, agg7, NT, G_TYP};
    s5_k<<<CTOT + NG + NT, 256, 0, stream>>>(pa, g2, t2);
  }
  // ---- S6: layer-1 gathers (series/users/writer + 3 embedding sets) ----
  {
    AggArgs a{};
    const int* aadj[6] = {adj0, adj1, adj4, adj2, adj3, adj5};
    const int* aoff[6] = {off0, off1, off4, off2, off3, off5};
    const float* ax[6] = {x0u, x0s, x0s, g_emb, w_emb, t_emb};
    float* aout[6] = {aggS0, agg1, agg5, aggS2, aggS4, aggS6};
    int aN[6] = {NS, NU, NW, NS, NS, NS};
    int s = 0;
    for (int i = 0; i < 6; ++i) {
      a.adj[i] = aadj[i]; a.off[i] = aoff[i]; a.x[i] = ax[i];
      a.out[i] = aout[i]; a.N[i] = aN[i];
      a.start[i] = s; s += (aN[i] + 15) / 16;
    }
    a.start[6] = s; a.ntask = 6;
    agg_fused<<<s, 256, 0, stream>>>(a);
  }
  // ---- S7: all layer-1 GEMMs ----
  {
    GemmMulti gm{};
    // series
    gm.g[0].seg[0] = {aggS0, WlH(0, 0), WlL(0, 0), 64};
    gm.g[0].seg[1] = {aggS2, WlH(0, 2), WlL(0, 2), 64};
    gm.g[0].seg[2] = {aggS4, WlH(0, 4), WlL(0, 4), 64};
    gm.g[0].seg[3] = {aggS6, WlH(0, 6), WlL(0, 6), 64};
    gm.g[0].seg[4] = {x0s, WrsH(0), WrsL(0), 64};
    gm.g[0].nseg = 5;
    gm.g[0].bias[0] = bl1 + 0 * 64; gm.g[0].bias[1] = bl1 + 2 * 64;
    gm.g[0].bias[2] = bl1 + 4 * 64; gm.g[0].bias[3] = bl1 + 6 * 64; gm.g[0].nbias = 4;
    gm.g[0].out = x1s; gm.g[0].M = NS; gm.g[0].relu = 1;
    // users
    gm.g[1].seg[0] = {agg1, WlH(0, 1), WlL(0, 1), 64};
    gm.g[1].seg[1] = {x0u, WrH(0, 1), WrL(0, 1), 64};
    gm.g[1].nseg = 2;
    gm.g[1].bias[0] = bl1 + 1 * 64; gm.g[1].nbias = 1;
    gm.g[1].out = x1u; gm.g[1].M = NU; gm.g[1].relu = 1;
    // writer
    gm.g[2].seg[0] = {agg5, WlH(0, 5), WlL(0, 5), 64};
    gm.g[2].seg[1] = {w_emb, WrH(0, 5), WrL(0, 5), 64};
    gm.g[2].nseg = 2;
    gm.g[2].bias[0] = bl1 + 5 * 64; gm.g[2].nbias = 1;
    gm.g[2].out = x1w; gm.g[2].M = NW; gm.g[2].relu = 1;
    // genres
    gm.g[3].seg[0] = {agg3, WlH(0, 3), WlL(0, 3), 64};
    gm.g[3].seg[1] = {g_emb, WrH(0, 3), WrL(0, 3), 64};
    gm.g[3].nseg = 2;
    gm.g[3].bias[0] = bl1 + 3 * 64; gm.g[3].nbias = 1;
    gm.g[3].out = x1g; gm.g[3].M = NG; gm.g[3].relu = 1;
    // type
    gm.g[4].seg[0] = {agg7, WlH(0, 7), WlL(0, 7), 64};
    gm.g[4].seg[1] = {t_emb, WrH(0, 7), WrL(0, 7), 64};
    gm.g[4].nseg = 2;
    gm.g[4].bias[0] = bl1 + 7 * 64; gm.g[4].nbias = 1;
    gm.g[4].out = x1t; gm.g[4].M = NT; gm.g[4].relu = 1;
    int mb[5] = {(NS + 63) / 64, (NU + 63) / 64, (NW + 63) / 64, 1, 1};
    int s = 0;
    for (int i = 0; i < 5; ++i) { gm.start[i] = s; s += mb[i]; }
    gm.start[5] = s; gm.n = 5;
    gemm_multi_k<<<s, 256, 0, stream>>>(gm);
  }
  // ---- S8: layer-2 gathers ----
  {
    AggArgs a{};
    const int* aadj[5] = {adj0, adj2, adj3, adj5, adj1};
    const int* aoff[5] = {off0, off2, off3, off5, off1};
    const float* ax[5] = {x1u, x1g, x1w, x1t, x1s};
    float* aout[5] = {aggS0, aggS2, aggS4, aggS6, agg1};
    int aN[5] = {NS, NS, NS, NS, NU};
    int s = 0;
    for (int i = 0; i < 5; ++i) {
      a.adj[i] = aadj[i]; a.off[i] = aoff[i]; a.x[i] = ax[i];
      a.out[i] = aout[i]; a.N[i] = aN[i];
      a.start[i] = s; s += (aN[i] + 15) / 16;
    }
    a.start[5] = s; a.start[6] = s; a.ntask = 5;
    agg_fused<<<s, 256, 0, stream>>>(a);
  }
  // ---- S9: layer-2 GEMMs ----
  {
    GemmMulti gm{};
    gm.g[0].seg[0] = {aggS0, WlH(1, 0), WlL(1, 0), 64};
    gm.g[0].seg[1] = {aggS2, WlH(1, 2), WlL(1, 2), 64};
    gm.g[0].seg[2] = {aggS4, WlH(1, 4), WlL(1, 4), 64};
    gm.g[0].seg[3] = {aggS6, WlH(1, 6), WlL(1, 6), 64};
    gm.g[0].seg[4] = {x1s, WrsH(1), WrsL(1), 64};
    gm.g[0].nseg = 5;
    gm.g[0].bias[0] = bl2 + 0 * 64; gm.g[0].bias[1] = bl2 + 2 * 64;
    gm.g[0].bias[2] = bl2 + 4 * 64; gm.g[0].bias[3] = bl2 + 6 * 64; gm.g[0].nbias = 4;
    gm.g[0].out = x2s; gm.g[0].M = NS; gm.g[0].relu = 0;
    gm.g[1].seg[0] = {agg1, WlH(1, 1), WlL(1, 1), 64};
    gm.g[1].seg[1] = {x1u, WrH(1, 1), WrL(1, 1), 64};
    gm.g[1].nseg = 2;
    gm.g[1].bias[0] = bl2 + 1 * 64; gm.g[1].nbias = 1;
    gm.g[1].out = x2u; gm.g[1].M = NU; gm.g[1].relu = 0;
    int s = 0;
    gm.start[0] = 0; s += (NS + 63) / 64;
    gm.start[1] = s; s += (NU + 63) / 64;
    gm.start[2] = s; gm.start[3] = s; gm.start[4] = s; gm.start[5] = s;
    gm.n = 2;
    gemm_multi_k<<<s, 256, 0, stream>>>(gm);
  }
  // ---- S10: scoring ----
  score_k<<<((long long)E_l * 64 + 255) / 256, 256, 0, stream>>>(
      eli, E_l, x2u, x2s, (float*)d_out);
}

// Round 8
// 736.397 us; speedup vs baseline: 1.0997x; 1.0997x over previous
//
#include <hip/hip_runtime.h>

#define NU 100000
#define NS 50000
#define NG 50
#define NW 20000
#define NT 10
#define CDIM 64
#define FDIM 384

typedef short bf16x8 __attribute__((ext_vector_type(8)));
typedef float f32x4 __attribute__((ext_vector_type(4)));
typedef unsigned short ushort;
typedef unsigned int uint;

#define CHUNK 128
#define CSHIFT 7
#define CMASK 127
#define NBINS 2503      // 391+782+391+391+157+391
#define PSTRIDE 800
#define BTOT 704        // fill/hist blocks (256+256+64+32+32+64) — R5 optimum
#define CTOT 2503
#define W_TOTAL 188416
#define WPB 736         // wprep blocks
#define G_GEN 512       // small1 genre blocks
#define G_TYP 256       // small1 type blocks
#define SCANB_BLK 626   // ceil(NBINS/4) wave-parallel scan blocks

struct PrepArgs {
  const int* src[6];
  const int* dst[6];
  int E[6];
  int nchunk[6];
  int nb[6];
  int cbase[7];
  int bbase[7];
  int cstart[7];
  int* partial;   // [BTOT][PSTRIDE]
  int* chunktot;  // [NBINS]
  int* choff;     // [NBINS + 6]
  int* bucket[6];
  int* adj[6];
  int* off[6];
};

struct WArgs {
  const float* Wu; const float* Wsp;
  const float* Wl1; const float* Wr1;
  const float* Wl2; const float* Wr2;
  ushort* S;
};

// ---------------- prep bodies ----------------
__device__ __forceinline__ void hist_body(const PrepArgs& a, int b, int t, int* bins) {
  int ty = 0;
  while (b >= a.bbase[ty + 1]) ++ty;
  int bl = b - a.bbase[ty], B = a.bbase[ty + 1] - a.bbase[ty];
  int n = a.nchunk[ty], E = a.E[ty];
  const int* __restrict__ dst = a.dst[ty];
  for (int i = t; i < n; i += 256) bins[i] = 0;
  __syncthreads();
  for (int i = bl * 256 + t; i < E; i += B * 256) atomicAdd(&bins[dst[i] >> CSHIFT], 1);
  __syncthreads();
  int* row = a.partial + (size_t)b * PSTRIDE;
  for (int i = t; i < n; i += 256) row[i] = bins[i];
}

// Wave-parallel scan over fill blocks for one bin (lane covers up to 8 blocks).
__device__ __forceinline__ void scanb_wave_body(const PrepArgs& a, int bin, int lane) {
  if (bin >= NBINS) return;
  int ty = 0;
  while (bin >= a.cbase[ty + 1]) ++ty;
  int l = bin - a.cbase[ty];
  int b0 = a.bbase[ty], B = a.bbase[ty + 1] - b0;
  int per = (B + 63) >> 6;   // 1..8
  int* pbase = a.partial + l;
  int v[8];
  int sum = 0;
#pragma unroll
  for (int k = 0; k < 8; ++k) {
    int idx = lane * per + k;
    int val = (k < per && idx < B) ? pbase[(size_t)(b0 + idx) * PSTRIDE] : 0;
    v[k] = sum; sum += val;
  }
  int run = sum;
#pragma unroll
  for (int d = 1; d < 64; d <<= 1) {
    int u = __shfl_up(run, d, 64);
    if (lane >= d) run += u;
  }
  int excl = run - sum;
#pragma unroll
  for (int k = 0; k < 8; ++k) {
    int idx = lane * per + k;
    if (k < per && idx < B) pbase[(size_t)(b0 + idx) * PSTRIDE] = excl + v[k];
  }
  if (lane == 63) a.chunktot[bin] = run;
}

__device__ __forceinline__ void scanc_body(const PrepArgs& a, int ty, int t, int* sc) {
  int n = a.nchunk[ty];
  int chunk = (n + 255) / 256;
  int lo = t * chunk, hi = min(n, lo + chunk);
  const int* __restrict__ cnt = a.chunktot + a.cbase[ty];
  int s = 0;
  for (int i = lo; i < hi; ++i) s += cnt[i];
  sc[t] = s;
  __syncthreads();
  for (int d = 1; d < 256; d <<= 1) {
    int u = (t >= d) ? sc[t - d] : 0;
    __syncthreads();
    sc[t] += u;
    __syncthreads();
  }
  int* choff = a.choff + a.cbase[ty] + ty;
  int carry = (t > 0) ? sc[t - 1] : 0;
  for (int i = lo; i < hi; ++i) { choff[i] = carry; carry += cnt[i]; }
  if (t == 255) choff[n] = sc[255];
}

__device__ __forceinline__ void fill_body(const PrepArgs& a, int b, int t, int* bins, int* base) {
  int ty = 0;
  while (b >= a.bbase[ty + 1]) ++ty;
  int bl = b - a.bbase[ty], B = a.bbase[ty + 1] - a.bbase[ty];
  int n = a.nchunk[ty], E = a.E[ty];
  const int* __restrict__ dst = a.dst[ty];
  const int* __restrict__ src = a.src[ty];
  int* __restrict__ bucket = a.bucket[ty];
  const int* choff = a.choff + a.cbase[ty] + ty;
  const int* prow = a.partial + (size_t)b * PSTRIDE;
  for (int i = t; i < n; i += 256) { bins[i] = 0; base[i] = choff[i] + prow[i]; }
  __syncthreads();
  for (int i = bl * 256 + t; i < E; i += B * 256) {
    int d = dst[i];
    int s = src[i];
    int l = d >> CSHIFT;
    int r = atomicAdd(&bins[l], 1);
    bucket[base[l] + r] = (s << CSHIFT) | (d & CMASK);
  }
}

__device__ __forceinline__ void csr_body(const PrepArgs& a, int b, int t,
                                         int* bins, int* sc, int* basea) {
  int ty = 0;
  while (b >= a.cstart[ty + 1]) ++ty;
  int c = b - a.cstart[ty];
  const int* __restrict__ bucket = a.bucket[ty];
  const int* choff = a.choff + a.cbase[ty] + ty;
  int beg = choff[c], end = choff[c + 1];
  if (t < CHUNK) bins[t] = 0;
  __syncthreads();
  for (int i = beg + t; i < end; i += 256) atomicAdd(&bins[bucket[i] & CMASK], 1);
  __syncthreads();
  int v = (t < CHUNK) ? bins[t] : 0;
  if (t < CHUNK) sc[t] = v;
  __syncthreads();
#pragma unroll
  for (int d = 1; d < CHUNK; d <<= 1) {
    int u = (t < CHUNK && t >= d) ? sc[t - d] : 0;
    __syncthreads();
    if (t < CHUNK) sc[t] += u;
    __syncthreads();
  }
  if (t < CHUNK) { basea[t] = beg + sc[t] - v; bins[t] = basea[t]; }
  __syncthreads();
  int gbase = c * CHUNK;
  int nb = a.nb[ty];
  if (t < CHUNK && gbase + t < nb) a.off[ty][gbase + t] = basea[t];
  if (b == a.cstart[ty + 1] - 1 && t == 0) a.off[ty][nb] = choff[a.nchunk[ty]];
  int* __restrict__ adj = a.adj[ty];
  for (int i = beg + t; i < end; i += 256) {
    int pk = bucket[i];
    int r = atomicAdd(&bins[pk & CMASK], 1);
    adj[r] = pk >> CSHIFT;
  }
}

// ---------------- weight split (pre-swizzled to MFMA B-fragment order) ------
__device__ __forceinline__ int swz_src(int u, int F) {
  int p = u >> 11;
  int nt = (u >> 9) & 3;
  int lane = (u >> 3) & 63;
  int j = u & 7;
  int row = nt * 16 + (lane & 15);
  int col = p * 32 + ((lane >> 4) << 3) + j;
  return row * F + col;
}

__device__ __forceinline__ void wprep_body(const WArgs& w, int i) {
  if (i >= W_TOTAL) return;
  float v;
  size_t hbase, lbase;
  int u;
  if (i < 24576) {
    u = i; hbase = 0; lbase = 24576;
    v = w.Wu[swz_src(u, FDIM)];
  } else if (i < 49152) {
    u = i - 24576; hbase = 49152; lbase = 73728;
    v = w.Wsp[swz_src(u, FDIM)];
  } else {
    int j = i - 49152;
    int layer = j / 69632;
    j %= 69632;
    const float* Wl = layer ? w.Wl2 : w.Wl1;
    const float* Wr = layer ? w.Wr2 : w.Wr1;
    size_t base = 98304 + (size_t)layer * 139264;
    if (j < 32768) {
      int s = j >> 12; u = j & 4095;
      hbase = base + (size_t)s * 4096; lbase = base + 32768 + (size_t)s * 4096;
      v = Wl[s * 4096 + swz_src(u, 64)];
    } else if (j < 65536) {
      int q = j - 32768; int s = q >> 12; u = q & 4095;
      hbase = base + 65536 + (size_t)s * 4096; lbase = base + 98304 + (size_t)s * 4096;
      v = Wr[s * 4096 + swz_src(u, 64)];
    } else {
      u = j - 65536;
      hbase = base + 131072; lbase = base + 135168;
      int si = swz_src(u, 64);
      v = Wr[si] + Wr[8192 + si] + Wr[16384 + si] + Wr[24576 + si];
    }
  }
  uint b = __float_as_uint(v);
  uint h = b & 0xFFFF0000u;
  float r = v - __uint_as_float(h);
  w.S[hbase + u] = (ushort)(h >> 16);
  w.S[lbase + u] = (ushort)(__float_as_uint(r) >> 16);
}

// ---------------- CSR gather (16-lane-group, float4 lanes) ----------------
__device__ __forceinline__ void csr_gather_body(const int* __restrict__ adj,
                                                const int* __restrict__ off,
                                                const float* __restrict__ x,
                                                float* __restrict__ out,
                                                int row, int l4, int gbase) {
  int beg = off[row], deg = off[row + 1] - beg;
  float4 a0 = {0.f, 0.f, 0.f, 0.f}, a1 = a0, a2 = a0, a3 = a0;
  int j = 0;
  while (j < deg) {
    int rem = min(deg - j, 16);
    int av = (l4 < rem) ? adj[beg + j + l4] : 0;
    int k = 0;
    for (; k + 4 <= rem; k += 4) {
      int s0 = __shfl(av, gbase + k + 0, 64);
      int s1 = __shfl(av, gbase + k + 1, 64);
      int s2 = __shfl(av, gbase + k + 2, 64);
      int s3 = __shfl(av, gbase + k + 3, 64);
      float4 v0 = *(const float4*)(x + (((size_t)s0) << 6) + l4 * 4);
      float4 v1 = *(const float4*)(x + (((size_t)s1) << 6) + l4 * 4);
      float4 v2 = *(const float4*)(x + (((size_t)s2) << 6) + l4 * 4);
      float4 v3 = *(const float4*)(x + (((size_t)s3) << 6) + l4 * 4);
      a0.x += v0.x; a0.y += v0.y; a0.z += v0.z; a0.w += v0.w;
      a1.x += v1.x; a1.y += v1.y; a1.z += v1.z; a1.w += v1.w;
      a2.x += v2.x; a2.y += v2.y; a2.z += v2.z; a2.w += v2.w;
      a3.x += v3.x; a3.y += v3.y; a3.z += v3.z; a3.w += v3.w;
    }
    for (; k < rem; ++k) {
      int s0 = __shfl(av, gbase + k, 64);
      float4 v0 = *(const float4*)(x + (((size_t)s0) << 6) + l4 * 4);
      a0.x += v0.x; a0.y += v0.y; a0.z += v0.z; a0.w += v0.w;
    }
    j += rem;
  }
  float4 s;
  s.x = (a0.x + a1.x) + (a2.x + a3.x);
  s.y = (a0.y + a1.y) + (a2.y + a3.y);
  s.z = (a0.z + a1.z) + (a2.z + a3.z);
  s.w = (a0.w + a1.w) + (a2.w + a3.w);
  float4 o = {0.f, 0.f, 0.f, 0.f};
  if (deg > 0) {
    float d = (float)deg;
    o.x = s.x / d; o.y = s.y / d; o.z = s.z / d; o.w = s.w / d;
  }
  *(float4*)(out + (((size_t)row) << 6) + l4 * 4) = o;
}

struct AggArgs {
  const int* adj[6];
  const int* off[6];
  const float* x[6];
  float* out[6];
  int N[6];
  int start[7];
  int ntask;
};

__global__ __launch_bounds__(256) void agg_fused(AggArgs a) {
  int b = blockIdx.x;
  int ti = 0;
  while (b >= a.start[ti + 1]) ++ti;
  int row = (b - a.start[ti]) * 16 + (threadIdx.x >> 4);
  int l4 = threadIdx.x & 15;
  int gbase = (threadIdx.x & 63) & 48;   // group base lane within wave
  if (row >= a.N[ti]) return;
  csr_gather_body(a.adj[ti], a.off[ti], a.x[ti], a.out[ti], row, l4, gbase);
}

// ---------------- small-dst agg (two-stage) ----------------
struct SmallT { const int* src; const int* dst; int E; const float* x;
                float* partial; int* pcnt; int nd; int G; };
struct Small2T { const float* partial; const int* pcnt; float* out; int nd; int G; };

__device__ __forceinline__ void small1_body(const SmallT& s, int blk, int t, int* smem) {
  float* acc = (float*)smem;
  int* cnt = smem + s.nd * CDIM;
  int lane = t & 63, wv = t >> 6;
  for (int i = t; i < s.nd * CDIM; i += 256) acc[i] = 0.f;
  for (int i = t; i < s.nd; i += 256) cnt[i] = 0;
  __syncthreads();
  const int* __restrict__ src = s.src;
  const int* __restrict__ dst = s.dst;
  const float* __restrict__ x = s.x;
  int E = s.E;
  for (int j0 = (blk * 4 + wv) * 64; j0 < E; j0 += s.G * 256) {
    int myj = j0 + lane;
    int sv = 0, dv = 0;
    if (myj < E) { sv = src[myj]; dv = dst[myj]; }
    int m = min(64, E - j0);
    int j = 0;
    for (; j + 4 <= m; j += 4) {
      int s0 = __shfl(sv, j, 64), s1 = __shfl(sv, j + 1, 64);
      int s2 = __shfl(sv, j + 2, 64), s3 = __shfl(sv, j + 3, 64);
      int d0 = __shfl(dv, j, 64), d1 = __shfl(dv, j + 1, 64);
      int d2 = __shfl(dv, j + 2, 64), d3 = __shfl(dv, j + 3, 64);
      float v0 = x[(size_t)s0 * CDIM + lane];
      float v1 = x[(size_t)s1 * CDIM + lane];
      float v2 = x[(size_t)s2 * CDIM + lane];
      float v3 = x[(size_t)s3 * CDIM + lane];
      atomicAdd(&acc[d0 * CDIM + lane], v0);
      atomicAdd(&acc[d1 * CDIM + lane], v1);
      atomicAdd(&acc[d2 * CDIM + lane], v2);
      atomicAdd(&acc[d3 * CDIM + lane], v3);
      if (lane == 0) {
        atomicAdd(&cnt[d0], 1); atomicAdd(&cnt[d1], 1);
        atomicAdd(&cnt[d2], 1); atomicAdd(&cnt[d3], 1);
      }
    }
    for (; j < m; ++j) {
      int sj = __shfl(sv, j, 64), dj = __shfl(dv, j, 64);
      atomicAdd(&acc[dj * CDIM + lane], x[(size_t)sj * CDIM + lane]);
      if (lane == 0) atomicAdd(&cnt[dj], 1);
    }
  }
  __syncthreads();
  float* po = s.partial + (size_t)blk * s.nd * CDIM;
  for (int i = t; i < s.nd * CDIM; i += 256) po[i] = acc[i];
  int* pc = s.pcnt + blk * s.nd;
  for (int i = t; i < s.nd; i += 256) pc[i] = cnt[i];
}

__device__ __forceinline__ void small2_body(const Small2T& s, int d, int t, int* smem) {
  float* red = (float*)smem;          // [4][64]
  int* redc = smem + 256;             // [4]
  int c = t & 63, sl = t >> 6;
  float sum = 0.f;
  int k = 0;
  for (int g = sl; g < s.G; g += 4) {
    sum += s.partial[(size_t)g * s.nd * CDIM + d * CDIM + c];
    if (c == 0) k += s.pcnt[g * s.nd + d];
  }
  red[sl * 64 + c] = sum;
  if (c == 0) redc[sl] = k;
  __syncthreads();
  if (sl == 0) {
    float tot = red[c] + red[64 + c] + red[128 + c] + red[192 + c];
    int kt = redc[0] + redc[1] + redc[2] + redc[3];
    s.out[d * CDIM + c] = (kt > 0) ? tot / (float)kt : 0.f;
  }
}

// ---------------- MFMA GEMM (bf16 hi/lo, pre-swizzled W) ----------------
struct GSeg { const float* A; const ushort* Wh; const ushort* Wl; int F; };
struct GArgs {
  GSeg seg[5];
  const float* bias[4];
  float* out;
  int nseg, nbias, M, relu;
};
struct GemmMulti { GArgs g[5]; int start[6]; int n; };

__device__ __forceinline__ void split8(const float* __restrict__ p, bf16x8& hi, bf16x8& lo) {
  float4 v0 = *(const float4*)p;
  float4 v1 = *(const float4*)(p + 4);
  float a[8] = {v0.x, v0.y, v0.z, v0.w, v1.x, v1.y, v1.z, v1.w};
  union { uint u[4]; bf16x8 v; } H, L;
#pragma unroll
  for (int i = 0; i < 4; ++i) {
    uint u0 = __float_as_uint(a[2 * i]), u1 = __float_as_uint(a[2 * i + 1]);
    uint h0 = u0 & 0xFFFF0000u, h1 = u1 & 0xFFFF0000u;
    float r0 = a[2 * i] - __uint_as_float(h0);
    float r1 = a[2 * i + 1] - __uint_as_float(h1);
    H.u[i] = (h0 >> 16) | h1;
    L.u[i] = ((__float_as_uint(r0) & 0xFFFF0000u) >> 16) | (__float_as_uint(r1) & 0xFFFF0000u);
  }
  hi = H.v;
  lo = L.v;
}

__device__ __forceinline__ void mfma_body(const GArgs& g, int mb, int tid) {
  const int lane = tid & 63, wv = tid >> 6;
  const int ln = lane & 15, quad = lane >> 4;
  const int m0 = mb * 64;
  f32x4 acc[4];
#pragma unroll
  for (int nt = 0; nt < 4; ++nt) acc[nt] = (f32x4){0.f, 0.f, 0.f, 0.f};

  const int ar = min(m0 + 16 * wv + ln, g.M - 1);

  for (int s = 0; s < g.nseg; ++s) {
    const float* __restrict__ A = g.seg[s].A;
    const ushort* __restrict__ whl = g.seg[s].Wh + (size_t)lane * 8;
    const ushort* __restrict__ wll = g.seg[s].Wl + (size_t)lane * 8;
    const int F = g.seg[s].F;
    const float* ap = A + (size_t)ar * F + quad * 8;
    for (int k0 = 0; k0 < F; k0 += 32) {
      bf16x8 ah, al;
      split8(ap + k0, ah, al);
      const size_t pb = (size_t)(k0 >> 5) * 2048;
#pragma unroll
      for (int nt = 0; nt < 4; ++nt) {
        bf16x8 bh = *(const bf16x8*)(whl + pb + nt * 512);
        bf16x8 bl = *(const bf16x8*)(wll + pb + nt * 512);
        acc[nt] = __builtin_amdgcn_mfma_f32_16x16x32_bf16(ah, bh, acc[nt], 0, 0, 0);
        acc[nt] = __builtin_amdgcn_mfma_f32_16x16x32_bf16(al, bh, acc[nt], 0, 0, 0);
        acc[nt] = __builtin_amdgcn_mfma_f32_16x16x32_bf16(ah, bl, acc[nt], 0, 0, 0);
      }
    }
  }

#pragma unroll
  for (int nt = 0; nt < 4; ++nt) {
    int c = nt * 16 + ln;
    float b = 0.f;
    for (int i = 0; i < g.nbias; ++i) b += g.bias[i][c];
#pragma unroll
    for (int r = 0; r < 4; ++r) {
      int m = m0 + 16 * wv + quad * 4 + r;
      if (m < g.M) {
        float o = acc[nt][r] + b;
        if (g.relu) o = fmaxf(o, 0.f);
        g.out[(size_t)m * CDIM + c] = o;
      }
    }
  }
}

__global__ __launch_bounds__(256) void gemm_multi_k(GemmMulti gm) {
  int b = blockIdx.x;
  int i = 0;
  while (b >= gm.start[i + 1]) ++i;
  mfma_body(gm.g[i], b - gm.start[i], threadIdx.x);
}

// ---------------- fused stage kernels ----------------
__global__ __launch_bounds__(256) void s1_k(PrepArgs pa, WArgs wa) {
  __shared__ int smem[PSTRIDE];
  int b = blockIdx.x;
  if (b < BTOT) hist_body(pa, b, threadIdx.x, smem);
  else wprep_body(wa, (b - BTOT) * 256 + threadIdx.x);
}

// S2: wave-parallel scanb + NS projection GEMM
__global__ __launch_bounds__(256) void s2_k(PrepArgs pa, GArgs g) {
  int b = blockIdx.x;
  if (b < SCANB_BLK) scanb_wave_body(pa, b * 4 + (threadIdx.x >> 6), threadIdx.x & 63);
  else mfma_body(g, b - SCANB_BLK, threadIdx.x);
}

// S3: scanc only (tiny; NU GEMM moved into S4 to overlap fill)
__global__ __launch_bounds__(256) void scanc_k(PrepArgs pa) {
  __shared__ int smem[256];
  scanc_body(pa, blockIdx.x, threadIdx.x, smem);
}

// S4: fill + small1(genre) + small1(type) + NU projection GEMM (overlap)
__global__ __launch_bounds__(256) void s4_k(PrepArgs pa, SmallT sg, SmallT st, GArgs g) {
  __shared__ int smem[3264];
  int b = blockIdx.x;
  if (b < BTOT) fill_body(pa, b, threadIdx.x, smem, smem + PSTRIDE);
  else if (b < BTOT + G_GEN) small1_body(sg, b - BTOT, threadIdx.x, smem);
  else if (b < BTOT + G_GEN + G_TYP) small1_body(st, b - BTOT - G_GEN, threadIdx.x, smem);
  else mfma_body(g, b - BTOT - G_GEN - G_TYP, threadIdx.x);
}

__global__ __launch_bounds__(256) void s5_k(PrepArgs pa, Small2T g2, Small2T t2) {
  __shared__ int smem[384];
  int b = blockIdx.x;
  if (b < CTOT) csr_body(pa, b, threadIdx.x, smem, smem + CHUNK, smem + 2 * CHUNK);
  else if (b < CTOT + NG) small2_body(g2, b - CTOT, threadIdx.x, smem);
  else small2_body(t2, b - CTOT - NG, threadIdx.x, smem);
}

// ---------------- scoring ----------------
__global__ __launch_bounds__(256) void score_k(const int* __restrict__ eli, int E,
                                               const float* __restrict__ xu,
                                               const float* __restrict__ xs,
                                               float* __restrict__ out) {
  long long gid = (long long)blockIdx.x * 256 + threadIdx.x;
  int e = (int)(gid >> 6);
  int c = (int)(gid & 63);
  if (e < E) {
    int u = eli[e];
    int sv = eli[E + e];
    float p = xu[(size_t)u * CDIM + c] * xs[(size_t)sv * CDIM + c];
#pragma unroll
    for (int off = 32; off > 0; off >>= 1) p += __shfl_down(p, off, 64);
    if (c == 0) out[e] = p;
  }
}

extern "C" void kernel_launch(void* const* d_in, const int* in_sizes, int n_in,
                              void* d_out, int out_size, void* d_ws, size_t ws_size,
                              hipStream_t stream) {
  const float* reviews  = (const float*)d_in[0];
  const float* overview = (const float*)d_in[1];
  const float* g_emb    = (const float*)d_in[2];
  const float* w_emb    = (const float*)d_in[3];
  const float* t_emb    = (const float*)d_in[4];
  const float* Wu  = (const float*)d_in[5];
  const float* bu  = (const float*)d_in[6];
  const float* Wsp = (const float*)d_in[7];
  const float* bs  = (const float*)d_in[8];
  const float* Wl1 = (const float*)d_in[9];
  const float* bl1 = (const float*)d_in[10];
  const float* Wr1 = (const float*)d_in[11];
  const float* Wl2 = (const float*)d_in[12];
  const float* bl2 = (const float*)d_in[13];
  const float* Wr2 = (const float*)d_in[14];
  const int* e_u2s = (const int*)d_in[15];
  const int* e_g2s = (const int*)d_in[16];
  const int* e_w2s = (const int*)d_in[17];
  const int* e_t2s = (const int*)d_in[18];
  const int* eli   = (const int*)d_in[19];
  const int E_u = in_sizes[15] / 2;
  const int E_g = in_sizes[16] / 2;
  const int E_w = in_sizes[17] / 2;
  const int E_t = in_sizes[18] / 2;
  const int E_l = in_sizes[19] / 2;

  // ---- workspace (ws_size ~614MB; we use ~200MB) ----
  float* ws = (float*)d_ws;
  size_t off = 0;
  auto take = [&](size_t n) { float* p = ws + off; off += n; return p; };
  float* x0u = take((size_t)NU * CDIM);
  float* x0s = take((size_t)NS * CDIM);
  float* x1u = take((size_t)NU * CDIM);
  float* x1s = take((size_t)NS * CDIM);
  float* x1g = take((size_t)NG * CDIM);
  float* x1w = take((size_t)NW * CDIM);
  float* x1t = take((size_t)NT * CDIM);
  float* aggS0 = take((size_t)NS * CDIM);
  float* aggS2 = take((size_t)NS * CDIM);
  float* aggS4 = take((size_t)NS * CDIM);
  float* aggS6 = take((size_t)NS * CDIM);
  float* agg1  = take((size_t)NU * CDIM);   // standalone (concurrent with aggS*)
  float* agg5  = take((size_t)NW * CDIM);
  float* agg3  = take((size_t)NG * CDIM);
  float* agg7  = take((size_t)NT * CDIM);
  float* spartG = take((size_t)G_GEN * NG * CDIM);
  int* spcntG   = (int*)take((size_t)G_GEN * NG);
  float* spartT = take((size_t)G_TYP * NT * CDIM);
  int* spcntT   = (int*)take((size_t)G_TYP * NT);
  ushort* wsplit = (ushort*)take((size_t)W_TOTAL);  // 2*W_TOTAL ushorts
  int* bkt0 = (int*)take(E_u);
  int* bkt1 = (int*)take(E_u);
  int* bkt2 = (int*)take(E_g);
  int* bkt3 = (int*)take(E_w);
  int* bkt4 = (int*)take(E_w);
  int* bkt5 = (int*)take(E_t);
  int* adj0 = (int*)take(E_u);
  int* adj1 = (int*)take(E_u);
  int* adj2 = (int*)take(E_g);
  int* adj3 = (int*)take(E_w);
  int* adj4 = (int*)take(E_w);
  int* adj5 = (int*)take(E_t);
  int* off0 = (int*)take(NS + 1);
  int* off1 = (int*)take(NU + 1);
  int* off2 = (int*)take(NS + 1);
  int* off3 = (int*)take(NS + 1);
  int* off4 = (int*)take(NW + 1);
  int* off5 = (int*)take(NS + 1);
  int* partial  = (int*)take((size_t)BTOT * PSTRIDE);
  int* chunktot = (int*)take(NBINS);
  int* choffG   = (int*)take(NBINS + 6);
  float* x2u = x0u;
  float* x2s = x0s;

  // split-weight region offsets (ushort units)
  const ushort* WuH = wsplit + 0;
  const ushort* WuL = wsplit + 24576;
  const ushort* WsH = wsplit + 49152;
  const ushort* WsL = wsplit + 73728;
  auto WlH = [&](int layer, int seg) { return wsplit + 98304 + (size_t)layer * 139264 + (size_t)seg * 4096; };
  auto WlL = [&](int layer, int seg) { return wsplit + 98304 + (size_t)layer * 139264 + 32768 + (size_t)seg * 4096; };
  auto WrH = [&](int layer, int seg) { return wsplit + 98304 + (size_t)layer * 139264 + 65536 + (size_t)seg * 4096; };
  auto WrL = [&](int layer, int seg) { return wsplit + 98304 + (size_t)layer * 139264 + 98304 + (size_t)seg * 4096; };
  auto WrsH = [&](int layer) { return wsplit + 98304 + (size_t)layer * 139264 + 131072; };
  auto WrsL = [&](int layer) { return wsplit + 98304 + (size_t)layer * 139264 + 135168; };

  // ---- prep args ----
  PrepArgs pa{};
  const int* bsrc[6] = {e_u2s, e_u2s + E_u, e_g2s, e_w2s, e_w2s + E_w, e_t2s};
  const int* bdst[6] = {e_u2s + E_u, e_u2s, e_g2s + E_g, e_w2s + E_w, e_w2s, e_t2s + E_t};
  int bE[6]  = {E_u, E_u, E_g, E_w, E_w, E_t};
  int nch[6] = {391, 782, 391, 391, 157, 391};
  int cb[7]  = {0, 391, 1173, 1564, 1955, 2112, 2503};
  int bpt[6] = {256, 256, 64, 32, 32, 64};
  int nbT[6] = {NS, NU, NS, NS, NW, NS};
  int* bkts[6] = {bkt0, bkt1, bkt2, bkt3, bkt4, bkt5};
  int* adjs[6] = {adj0, adj1, adj2, adj3, adj4, adj5};
  int* offs[6] = {off0, off1, off2, off3, off4, off5};
  int bb = 0, cs = 0;
  for (int i = 0; i < 6; ++i) {
    pa.src[i] = bsrc[i]; pa.dst[i] = bdst[i]; pa.E[i] = bE[i];
    pa.nchunk[i] = nch[i]; pa.nb[i] = nbT[i]; pa.cbase[i] = cb[i];
    pa.bbase[i] = bb; bb += bpt[i];
    pa.cstart[i] = cs; cs += nch[i];
    pa.bucket[i] = bkts[i]; pa.adj[i] = adjs[i]; pa.off[i] = offs[i];
  }
  pa.cbase[6] = cb[6]; pa.bbase[6] = bb; pa.cstart[6] = cs;
  pa.partial = partial; pa.chunktot = chunktot; pa.choff = choffG;

  WArgs wa{Wu, Wsp, Wl1, Wr1, Wl2, Wr2, wsplit};

  // ---- S1: hist + weight split ----
  s1_k<<<BTOT + WPB, 256, 0, stream>>>(pa, wa);

  // ---- S2: scanb (wave-parallel) + NS projection ----
  {
    GArgs g{};
    g.seg[0] = {overview, WsH, WsL, FDIM}; g.nseg = 1;
    g.bias[0] = bs; g.nbias = 1;
    g.out = x0s; g.M = NS; g.relu = 0;
    s2_k<<<SCANB_BLK + (NS + 63) / 64, 256, 0, stream>>>(pa, g);
  }
  // ---- S3: scanc (tiny) ----
  scanc_k<<<6, 256, 0, stream>>>(pa);
  // ---- S4: fill + small1(genres) + small1(type) + NU projection GEMM ----
  {
    SmallT sg{e_g2s, e_g2s + E_g, E_g, x0s, spartG, spcntG, NG, G_GEN};
    SmallT st{e_t2s, e_t2s + E_t, E_t, x0s, spartT, spcntT, NT, G_TYP};
    sg.src = e_g2s + E_g; sg.dst = e_g2s;
    st.src = e_t2s + E_t; st.dst = e_t2s;
    GArgs g{};
    g.seg[0] = {reviews, WuH, WuL, FDIM}; g.nseg = 1;
    g.bias[0] = bu; g.nbias = 1;
    g.out = x0u; g.M = NU; g.relu = 0;
    s4_k<<<BTOT + G_GEN + G_TYP + (NU + 63) / 64, 256, 0, stream>>>(pa, sg, st, g);
  }
  // ---- S5: csr + small2(genres) + small2(type) ----
  {
    Small2T g2{spartG, spcntG, agg3, NG, G_GEN};
    Small2T t2{spartT, spcntT, agg7, NT, G_TYP};
    s5_k<<<CTOT + NG + NT, 256, 0, stream>>>(pa, g2, t2);
  }
  // ---- S6: layer-1 gathers (series/users/writer + 3 embedding sets) ----
  {
    AggArgs a{};
    const int* aadj[6] = {adj0, adj1, adj4, adj2, adj3, adj5};
    const int* aoff[6] = {off0, off1, off4, off2, off3, off5};
    const float* ax[6] = {x0u, x0s, x0s, g_emb, w_emb, t_emb};
    float* aout[6] = {aggS0, agg1, agg5, aggS2, aggS4, aggS6};
    int aN[6] = {NS, NU, NW, NS, NS, NS};
    int s = 0;
    for (int i = 0; i < 6; ++i) {
      a.adj[i] = aadj[i]; a.off[i] = aoff[i]; a.x[i] = ax[i];
      a.out[i] = aout[i]; a.N[i] = aN[i];
      a.start[i] = s; s += (aN[i] + 15) / 16;
    }
    a.start[6] = s; a.ntask = 6;
    agg_fused<<<s, 256, 0, stream>>>(a);
  }
  // ---- S7: all layer-1 GEMMs ----
  {
    GemmMulti gm{};
    // series
    gm.g[0].seg[0] = {aggS0, WlH(0, 0), WlL(0, 0), 64};
    gm.g[0].seg[1] = {aggS2, WlH(0, 2), WlL(0, 2), 64};
    gm.g[0].seg[2] = {aggS4, WlH(0, 4), WlL(0, 4), 64};
    gm.g[0].seg[3] = {aggS6, WlH(0, 6), WlL(0, 6), 64};
    gm.g[0].seg[4] = {x0s, WrsH(0), WrsL(0), 64};
    gm.g[0].nseg = 5;
    gm.g[0].bias[0] = bl1 + 0 * 64; gm.g[0].bias[1] = bl1 + 2 * 64;
    gm.g[0].bias[2] = bl1 + 4 * 64; gm.g[0].bias[3] = bl1 + 6 * 64; gm.g[0].nbias = 4;
    gm.g[0].out = x1s; gm.g[0].M = NS; gm.g[0].relu = 1;
    // users
    gm.g[1].seg[0] = {agg1, WlH(0, 1), WlL(0, 1), 64};
    gm.g[1].seg[1] = {x0u, WrH(0, 1), WrL(0, 1), 64};
    gm.g[1].nseg = 2;
    gm.g[1].bias[0] = bl1 + 1 * 64; gm.g[1].nbias = 1;
    gm.g[1].out = x1u; gm.g[1].M = NU; gm.g[1].relu = 1;
    // writer
    gm.g[2].seg[0] = {agg5, WlH(0, 5), WlL(0, 5), 64};
    gm.g[2].seg[1] = {w_emb, WrH(0, 5), WrL(0, 5), 64};
    gm.g[2].nseg = 2;
    gm.g[2].bias[0] = bl1 + 5 * 64; gm.g[2].nbias = 1;
    gm.g[2].out = x1w; gm.g[2].M = NW; gm.g[2].relu = 1;
    // genres
    gm.g[3].seg[0] = {agg3, WlH(0, 3), WlL(0, 3), 64};
    gm.g[3].seg[1] = {g_emb, WrH(0, 3), WrL(0, 3), 64};
    gm.g[3].nseg = 2;
    gm.g[3].bias[0] = bl1 + 3 * 64; gm.g[3].nbias = 1;
    gm.g[3].out = x1g; gm.g[3].M = NG; gm.g[3].relu = 1;
    // type
    gm.g[4].seg[0] = {agg7, WlH(0, 7), WlL(0, 7), 64};
    gm.g[4].seg[1] = {t_emb, WrH(0, 7), WrL(0, 7), 64};
    gm.g[4].nseg = 2;
    gm.g[4].bias[0] = bl1 + 7 * 64; gm.g[4].nbias = 1;
    gm.g[4].out = x1t; gm.g[4].M = NT; gm.g[4].relu = 1;
    int mb[5] = {(NS + 63) / 64, (NU + 63) / 64, (NW + 63) / 64, 1, 1};
    int s = 0;
    for (int i = 0; i < 5; ++i) { gm.start[i] = s; s += mb[i]; }
    gm.start[5] = s; gm.n = 5;
    gemm_multi_k<<<s, 256, 0, stream>>>(gm);
  }
  // ---- S8: layer-2 gathers ----
  {
    AggArgs a{};
    const int* aadj[5] = {adj0, adj2, adj3, adj5, adj1};
    const int* aoff[5] = {off0, off2, off3, off5, off1};
    const float* ax[5] = {x1u, x1g, x1w, x1t, x1s};
    float* aout[5] = {aggS0, aggS2, aggS4, aggS6, agg1};
    int aN[5] = {NS, NS, NS, NS, NU};
    int s = 0;
    for (int i = 0; i < 5; ++i) {
      a.adj[i] = aadj[i]; a.off[i] = aoff[i]; a.x[i] = ax[i];
      a.out[i] = aout[i]; a.N[i] = aN[i];
      a.start[i] = s; s += (aN[i] + 15) / 16;
    }
    a.start[5] = s; a.start[6] = s; a.ntask = 5;
    agg_fused<<<s, 256, 0, stream>>>(a);
  }
  // ---- S9: layer-2 GEMMs ----
  {
    GemmMulti gm{};
    gm.g[0].seg[0] = {aggS0, WlH(1, 0), WlL(1, 0), 64};
    gm.g[0].seg[1] = {aggS2, WlH(1, 2), WlL(1, 2), 64};
    gm.g[0].seg[2] = {aggS4, WlH(1, 4), WlL(1, 4), 64};
    gm.g[0].seg[3] = {aggS6, WlH(1, 6), WlL(1, 6), 64};
    gm.g[0].seg[4] = {x1s, WrsH(1), WrsL(1), 64};
    gm.g[0].nseg = 5;
    gm.g[0].bias[0] = bl2 + 0 * 64; gm.g[0].bias[1] = bl2 + 2 * 64;
    gm.g[0].bias[2] = bl2 + 4 * 64; gm.g[0].bias[3] = bl2 + 6 * 64; gm.g[0].nbias = 4;
    gm.g[0].out = x2s; gm.g[0].M = NS; gm.g[0].relu = 0;
    gm.g[1].seg[0] = {agg1, WlH(1, 1), WlL(1, 1), 64};
    gm.g[1].seg[1] = {x1u, WrH(1, 1), WrL(1, 1), 64};
    gm.g[1].nseg = 2;
    gm.g[1].bias[0] = bl2 + 1 * 64; gm.g[1].nbias = 1;
    gm.g[1].out = x2u; gm.g[1].M = NU; gm.g[1].relu = 0;
    int s = 0;
    gm.start[0] = 0; s += (NS + 63) / 64;
    gm.start[1] = s; s += (NU + 63) / 64;
    gm.start[2] = s; gm.start[3] = s; gm.start[4] = s; gm.start[5] = s;
    gm.n = 2;
    gemm_multi_k<<<s, 256, 0, stream>>>(gm);
  }
  // ---- S10: scoring ----
  score_k<<<((long long)E_l * 64 + 255) / 256, 256, 0, stream>>>(
      eli, E_l, x2u, x2s, (float*)d_out);
}